// Round 2
// baseline (443.991 us; speedup 1.0000x reference)
//
#include <hip/hip_runtime.h>

#define NV 12
#define CIN 384
#define COUT 32
#define HW 4096        // 64*64 feature pixels
#define NVOX 262144    // 64^3 voxels
#define CSPLIT 4
#define CPER (CIN / CSPLIT)   // 96 channels per split
#define PIXT 128              // pixels per block

// Tiny prep: transpose w (32x384) -> wt (384x32) so the reduce kernel's
// weight reads are contiguous uniform loads (s_load_dwordx).
__global__ __launch_bounds__(256) void w_transpose_kernel(
    const float* __restrict__ w, float* __restrict__ wt)
{
    const int idx = blockIdx.x * 256 + threadIdx.x;   // 0..12287
    const int c = idx >> 5, o = idx & 31;
    wt[idx] = w[o * CIN + c];
}

// Kernel 1: channel reduction 384 -> 32, K-split 4 ways for occupancy.
// Block: 512 threads = 4 channel-splits x 128 pixels. Each thread reduces
// 96 channels into 32 accumulators; LDS tree combines the 4 partials.
__global__ __launch_bounds__(512) void mv_reduce_kernel(
    const float* __restrict__ vit, const float* __restrict__ wt,
    const float* __restrict__ bias, float* __restrict__ feats)
{
    __shared__ float red[2][PIXT][COUT];   // 32 KiB

    const int tid   = threadIdx.x;
    const int p     = tid & (PIXT - 1);
    const int split = tid >> 7;            // 0..3
    const int bv    = blockIdx.x;          // 0..47
    const int pix   = blockIdx.y * PIXT + p;

    const float* src = vit + ((size_t)bv * CIN + split * CPER) * HW + pix;
    const float* wr  = wt + split * CPER * COUT;

    float acc[COUT];
#pragma unroll
    for (int o = 0; o < COUT; ++o) acc[o] = 0.0f;

#pragma unroll 4
    for (int c = 0; c < CPER; ++c) {
        const float x = src[(size_t)c * HW];
#pragma unroll
        for (int o = 0; o < COUT; ++o)
            acc[o] = fmaf(x, wr[c * COUT + o], acc[o]);
    }

    // LDS tree-reduce across the 4 splits. float4 stores with a per-pixel
    // rotated column so each 8-lane group covers all 32 banks (conflict-free).
    const int rot = p & 7;

    if (split >= 2) {
#pragma unroll
        for (int o4 = 0; o4 < 8; ++o4) {
            const int col = ((o4 + rot) & 7) << 2;
            *reinterpret_cast<float4*>(&red[split - 2][p][col]) =
                make_float4(acc[o4 * 4], acc[o4 * 4 + 1], acc[o4 * 4 + 2], acc[o4 * 4 + 3]);
        }
    }
    __syncthreads();
    if (split < 2) {
#pragma unroll
        for (int o4 = 0; o4 < 8; ++o4) {
            const int col = ((o4 + rot) & 7) << 2;
            const float4 f = *reinterpret_cast<const float4*>(&red[split][p][col]);
            acc[o4 * 4] += f.x; acc[o4 * 4 + 1] += f.y;
            acc[o4 * 4 + 2] += f.z; acc[o4 * 4 + 3] += f.w;
        }
    }
    __syncthreads();
    if (split == 1) {
#pragma unroll
        for (int o4 = 0; o4 < 8; ++o4) {
            const int col = ((o4 + rot) & 7) << 2;
            *reinterpret_cast<float4*>(&red[0][p][col]) =
                make_float4(acc[o4 * 4], acc[o4 * 4 + 1], acc[o4 * 4 + 2], acc[o4 * 4 + 3]);
        }
    }
    __syncthreads();
    if (split == 0) {
        float* dst = feats + ((size_t)bv * HW + pix) * COUT;
#pragma unroll
        for (int o4 = 0; o4 < 8; ++o4) {
            const int col = ((o4 + rot) & 7) << 2;
            const float4 f = *reinterpret_cast<const float4*>(&red[0][p][col]);
            *reinterpret_cast<float4*>(dst + o4 * 4) = make_float4(
                acc[o4 * 4]     + f.x + bias[o4 * 4],
                acc[o4 * 4 + 1] + f.y + bias[o4 * 4 + 1],
                acc[o4 * 4 + 2] + f.z + bias[o4 * 4 + 2],
                acc[o4 * 4 + 3] + f.w + bias[o4 * 4 + 3]);
        }
    }
}

// Kernel 2: backproject voxels into each view, gather 32-ch features, average.
// One thread per (b, voxel). Projection math in fp64 (round decisions exact;
// rint = round-half-even matches jnp.round).
__global__ __launch_bounds__(256) void mv_fuse_kernel(
    const float* __restrict__ feats, const float* __restrict__ proj,
    float* __restrict__ out)
{
    __shared__ double P[NV][12];

    const int tid = threadIdx.x;
    const unsigned gid = blockIdx.x * 256u + tid;
    const int b = gid >> 18;            // 262144 voxels per batch
    const int n = gid & (NVOX - 1);

    if (tid < NV * 12) {
        const int v = tid / 12, e = tid - v * 12;
        const int r = e >> 2;                       // row 0..2
        const float s = (r < 2) ? 0.25f : 1.0f;     // projection[:, :, :2, :] / STRIDE
        P[v][e] = (double)(proj[((b * NV + v) * 3 + r) * 4 + (e & 3)] * s);
    }
    __syncthreads();

    const int k = n & 63, j = (n >> 6) & 63, i = n >> 12;
    const double wx = (double)i * 0.04 - 1.28;
    const double wy = (double)j * 0.04 - 1.28;
    const double wz = (double)k * 0.04 - 1.28;

    float acc[COUT];
#pragma unroll
    for (int o = 0; o < COUT; ++o) acc[o] = 0.0f;
    int cnt = 0;

    const float* fb = feats + (size_t)b * NV * HW * COUT;

    for (int v = 0; v < NV; ++v) {
        const double* p = P[v];
        const double cz = p[8] * wx + p[9] * wy + p[10] * wz + p[11];
        if (!(cz > 0.0)) continue;
        const double cx = p[0] * wx + p[1] * wy + p[2] * wz + p[3];
        const double cy = p[4] * wx + p[5] * wy + p[6] * wz + p[7];
        const double u = rint(cx / cz);   // round-half-even == jnp.round
        const double t = rint(cy / cz);
        if (u < 0.0 || u > 63.0 || t < 0.0 || t > 63.0) continue;
        const int px = (int)u, py = (int)t;

        const float4* s4 = reinterpret_cast<const float4*>(
            fb + ((size_t)(v * HW + py * 64 + px)) * COUT);
        ++cnt;
#pragma unroll
        for (int q = 0; q < 8; ++q) {
            const float4 f = s4[q];
            acc[q * 4 + 0] += f.x;
            acc[q * 4 + 1] += f.y;
            acc[q * 4 + 2] += f.z;
            acc[q * 4 + 3] += f.w;
        }
    }

    const float sc = (cnt > 0) ? (1.0f / (float)cnt) : 0.0f;
    float* ob = out + (size_t)b * COUT * NVOX + n;
#pragma unroll
    for (int o = 0; o < COUT; ++o)
        ob[(size_t)o * NVOX] = acc[o] * sc;
}

extern "C" void kernel_launch(void* const* d_in, const int* in_sizes, int n_in,
                              void* d_out, int out_size, void* d_ws, size_t ws_size,
                              hipStream_t stream) {
    const float* vit  = (const float*)d_in[0];  // (4,12,384,64,64)
    const float* w    = (const float*)d_in[1];  // (32,384)
    const float* bias = (const float*)d_in[2];  // (32,)
    const float* proj = (const float*)d_in[3];  // (4,12,3,4)
    float* out = (float*)d_out;                 // (4,32,64,64,64)

    float* wt    = (float*)d_ws;                // 384*32 floats = 48 KiB
    float* feats = wt + CIN * COUT;             // 48*4096*32 floats = 25.2 MB

    w_transpose_kernel<<<48, 256, 0, stream>>>(w, wt);

    dim3 g1(48, HW / PIXT);                     // 48 x 32 blocks, 512 threads
    mv_reduce_kernel<<<g1, 512, 0, stream>>>(vit, wt, bias, feats);

    mv_fuse_kernel<<<4096, 256, 0, stream>>>(feats, proj, out);
}

// Round 3
// 271.886 us; speedup vs baseline: 1.6330x; 1.6330x over previous
//
#include <hip/hip_runtime.h>

#define NV 12
#define CIN 384
#define COUT 32
#define HW 4096        // 64*64 feature pixels
#define NVOX 262144    // 64^3 voxels
#define CSPLIT 2
#define CPER (CIN / CSPLIT)   // 192 channels per split
#define PIXT 256              // pixels per block
#define NP4 (48 * HW * (COUT / 4))   // float4 count of one partial buffer

// Kernel 1: channel reduction partials. K split across blockIdx.z (wave-uniform
// -> weight loads scalarize to s_load; the FMA weight operand is an SGPR).
// CRITICAL: no threadIdx in the weight index chain (round-2 lesson: divergent
// weight addresses demote to 32 VMEM loads/channel and double runtime).
__global__ __launch_bounds__(256) void mv_reduce_kernel(
    const float* __restrict__ vit, const float* __restrict__ w,
    float* __restrict__ pbuf)
{
    const int bv    = blockIdx.x;                       // 0..47
    const int split = blockIdx.z;                       // 0..CSPLIT-1 (uniform)
    const int pix   = blockIdx.y * PIXT + threadIdx.x;  // 0..4095

    const float* src = vit + ((size_t)bv * CIN + split * CPER) * HW + pix;
    const float* wr  = w + split * CPER;                // w[o*CIN + split*CPER + c]

    float acc[COUT];
#pragma unroll
    for (int o = 0; o < COUT; ++o) acc[o] = 0.0f;

#pragma unroll 8
    for (int c = 0; c < CPER; ++c) {
        const float x = src[(size_t)c * HW];
#pragma unroll
        for (int o = 0; o < COUT; ++o)
            acc[o] = fmaf(x, wr[o * CIN + c], acc[o]);
    }

    float* dst = pbuf + (((size_t)split * 48 + bv) * HW + pix) * COUT;
#pragma unroll
    for (int o = 0; o < COUT; o += 4)
        *reinterpret_cast<float4*>(dst + o) =
            make_float4(acc[o], acc[o + 1], acc[o + 2], acc[o + 3]);
}

// Kernel 1b: combine the CSPLIT partials + bias -> feats[bv][pix][o].
__global__ __launch_bounds__(256) void mv_combine_kernel(
    const float* __restrict__ pbuf, const float* __restrict__ bias,
    float* __restrict__ feats)
{
    const int f = blockIdx.x * 256 + threadIdx.x;       // float4 index
    const float4 a = reinterpret_cast<const float4*>(pbuf)[f];
    const float4 b = reinterpret_cast<const float4*>(pbuf)[f + NP4];
    const float4 bs = reinterpret_cast<const float4*>(bias)[f & 7];
    reinterpret_cast<float4*>(feats)[f] =
        make_float4(a.x + b.x + bs.x, a.y + b.y + bs.y,
                    a.z + b.z + bs.z, a.w + b.w + bs.w);
}

// Kernel 2: backproject voxels into each view, gather 32-ch features, average.
// One thread per (b, voxel). Projection math in fp64 (round decisions exact;
// rint = round-half-even matches jnp.round).
__global__ __launch_bounds__(256) void mv_fuse_kernel(
    const float* __restrict__ feats, const float* __restrict__ proj,
    float* __restrict__ out)
{
    __shared__ double P[NV][12];

    const int tid = threadIdx.x;
    const unsigned gid = blockIdx.x * 256u + tid;
    const int b = gid >> 18;            // 262144 voxels per batch
    const int n = gid & (NVOX - 1);

    if (tid < NV * 12) {
        const int v = tid / 12, e = tid - v * 12;
        const int r = e >> 2;                       // row 0..2
        const float s = (r < 2) ? 0.25f : 1.0f;     // projection[:, :, :2, :] / STRIDE
        P[v][e] = (double)(proj[((b * NV + v) * 3 + r) * 4 + (e & 3)] * s);
    }
    __syncthreads();

    const int k = n & 63, j = (n >> 6) & 63, i = n >> 12;
    const double wx = (double)i * 0.04 - 1.28;
    const double wy = (double)j * 0.04 - 1.28;
    const double wz = (double)k * 0.04 - 1.28;

    float acc[COUT];
#pragma unroll
    for (int o = 0; o < COUT; ++o) acc[o] = 0.0f;
    int cnt = 0;

    const float* fb = feats + (size_t)b * NV * HW * COUT;

    for (int v = 0; v < NV; ++v) {
        const double* p = P[v];
        const double cz = p[8] * wx + p[9] * wy + p[10] * wz + p[11];
        if (!(cz > 0.0)) continue;
        const double cx = p[0] * wx + p[1] * wy + p[2] * wz + p[3];
        const double cy = p[4] * wx + p[5] * wy + p[6] * wz + p[7];
        const double u = rint(cx / cz);   // round-half-even == jnp.round
        const double t = rint(cy / cz);
        if (u < 0.0 || u > 63.0 || t < 0.0 || t > 63.0) continue;
        const int px = (int)u, py = (int)t;

        const float4* s4 = reinterpret_cast<const float4*>(
            fb + ((size_t)(v * HW + py * 64 + px)) * COUT);
        ++cnt;
#pragma unroll
        for (int q = 0; q < 8; ++q) {
            const float4 f = s4[q];
            acc[q * 4 + 0] += f.x;
            acc[q * 4 + 1] += f.y;
            acc[q * 4 + 2] += f.z;
            acc[q * 4 + 3] += f.w;
        }
    }

    const float sc = (cnt > 0) ? (1.0f / (float)cnt) : 0.0f;
    float* ob = out + (size_t)b * COUT * NVOX + n;
#pragma unroll
    for (int o = 0; o < COUT; ++o)
        ob[(size_t)o * NVOX] = acc[o] * sc;
}

extern "C" void kernel_launch(void* const* d_in, const int* in_sizes, int n_in,
                              void* d_out, int out_size, void* d_ws, size_t ws_size,
                              hipStream_t stream) {
    const float* vit  = (const float*)d_in[0];  // (4,12,384,64,64)
    const float* w    = (const float*)d_in[1];  // (32,384)
    const float* bias = (const float*)d_in[2];  // (32,)
    const float* proj = (const float*)d_in[3];  // (4,12,3,4)
    float* out = (float*)d_out;                 // (4,32,64,64,64) = 134 MB

    // Partials (2 x 25.2 MB = 50.3 MB) live in d_out (134 MB, proven);
    // fuse overwrites all of d_out at the end. feats (25.2 MB) in d_ws.
    float* pbuf  = out;
    float* feats = (float*)d_ws;

    dim3 g1(48, HW / PIXT, CSPLIT);             // 48 x 16 x 2 blocks, 256 thr
    mv_reduce_kernel<<<g1, 256, 0, stream>>>(vit, w, pbuf);

    mv_combine_kernel<<<NP4 / 256, 256, 0, stream>>>(pbuf, bias, feats);

    mv_fuse_kernel<<<4096, 256, 0, stream>>>(feats, proj, out);
}

// Round 4
// 184.126 us; speedup vs baseline: 2.4113x; 1.4766x over previous
//
#include <hip/hip_runtime.h>

#define NV 12
#define CIN 384
#define COUT 32
#define HW 4096        // 64*64 feature pixels
#define NVOX 262144    // 64^3 voxels
#define KSTEPS 12      // 384 / 32

typedef __attribute__((ext_vector_type(8))) short short8v;   // 8 bf16 (4 VGPR)
typedef __attribute__((ext_vector_type(4))) float f32x4;     // MFMA accum

// fp32 -> bf16 bits, round-to-nearest-even (finite data; NaN not handled).
__device__ __forceinline__ short bf16b(float x) {
    union { float f; unsigned u; } c; c.f = x;
    unsigned r = (c.u + 0x7fffu + ((c.u >> 16) & 1u)) >> 16;
    return (short)r;
}

// Prep: repack W (32x384 fp32) into MFMA A-fragment order, bf16:
// wfrag[((s*4+g)*32 + o)*8 + i] = bf16(w[o*384 + s*32 + g*8 + i])
// so the main kernel's A-frag load is ONE dwordx4 per (s, g, o-tile).
__global__ __launch_bounds__(256) void w_prep_kernel(
    const float* __restrict__ w, short* __restrict__ wfrag)
{
    const int t = blockIdx.x * 256 + threadIdx.x;   // 0..1535
    if (t >= 48 * 32) return;
    const int sg = t >> 5, o = t & 31;
    const int s = sg >> 2, g = sg & 3;
    short8v v;
#pragma unroll
    for (int i = 0; i < 8; ++i)
        v[i] = bf16b(w[o * CIN + s * 32 + g * 8 + i]);
    *reinterpret_cast<short8v*>(wfrag + t * 8) = v;
}

// Kernel 1: channel reduce 384->32 on the matrix cores.
// One wave per (bv, 16-pixel tile). B-frag (vit) loaded straight from global
// (lane: pix = l&15, k = 8*(l>>4)+i -> 16-lane groups read 64B contiguous),
// converted to bf16 in-register. A-frag from the pre-packed wfrag (L1-hot).
// D layout (verified): col(pix) = l&15, row(o) = 4*(l>>4)+reg.
__global__ __launch_bounds__(256) void mv_reduce_mfma_kernel(
    const float* __restrict__ vit, const short* __restrict__ wfrag,
    const float* __restrict__ bias, float* __restrict__ feats)
{
    const int bid  = blockIdx.x;            // 0..3071
    const int bv   = bid >> 6;              // 0..47
    const int wave = threadIdx.x >> 6;      // 0..3
    const int pix0 = ((bid & 63) * 4 + wave) * 16;

    const int l   = threadIdx.x & 63;
    const int col = l & 15;                 // pixel within tile / o within tile
    const int g   = l >> 4;                 // k-group

    const float* vp = vit + (size_t)bv * CIN * HW + (size_t)g * 8 * HW + pix0 + col;
    const short8v* wf = reinterpret_cast<const short8v*>(wfrag);

    f32x4 acc0 = {0.f, 0.f, 0.f, 0.f};
    f32x4 acc1 = {0.f, 0.f, 0.f, 0.f};

#pragma unroll
    for (int s = 0; s < KSTEPS; ++s) {
        const short8v a0 = wf[(s * 4 + g) * 32 + col];        // o = col
        const short8v a1 = wf[(s * 4 + g) * 32 + 16 + col];   // o = 16 + col

        float xb[8];
#pragma unroll
        for (int i = 0; i < 8; ++i)
            xb[i] = vp[(size_t)(s * 32 + i) * HW];

        short8v bfr;
#pragma unroll
        for (int i = 0; i < 8; ++i) bfr[i] = bf16b(xb[i]);

        acc0 = __builtin_amdgcn_mfma_f32_16x16x32_bf16(a0, bfr, acc0, 0, 0, 0);
        acc1 = __builtin_amdgcn_mfma_f32_16x16x32_bf16(a1, bfr, acc1, 0, 0, 0);
    }

    // Store: feats[pix][o], lane's 4 accum elems are o-contiguous (o = 4g+r).
    float* dst = feats + ((size_t)bv * HW + pix0 + col) * COUT;
    const float4 b0 = *reinterpret_cast<const float4*>(bias + 4 * g);
    const float4 b1 = *reinterpret_cast<const float4*>(bias + 16 + 4 * g);
    *reinterpret_cast<float4*>(dst + 4 * g) =
        make_float4(acc0[0] + b0.x, acc0[1] + b0.y, acc0[2] + b0.z, acc0[3] + b0.w);
    *reinterpret_cast<float4*>(dst + 16 + 4 * g) =
        make_float4(acc1[0] + b1.x, acc1[1] + b1.y, acc1[2] + b1.z, acc1[3] + b1.w);
}

// Kernel 2: backproject voxels into each view, gather 32-ch features, average.
// One thread per (b, voxel). Projection math in fp64 (round decisions exact;
// rint = round-half-even matches jnp.round).
__global__ __launch_bounds__(256) void mv_fuse_kernel(
    const float* __restrict__ feats, const float* __restrict__ proj,
    float* __restrict__ out)
{
    __shared__ double P[NV][12];

    const int tid = threadIdx.x;
    const unsigned gid = blockIdx.x * 256u + tid;
    const int b = gid >> 18;            // 262144 voxels per batch
    const int n = gid & (NVOX - 1);

    if (tid < NV * 12) {
        const int v = tid / 12, e = tid - v * 12;
        const int r = e >> 2;                       // row 0..2
        const float s = (r < 2) ? 0.25f : 1.0f;     // projection[:, :, :2, :] / STRIDE
        P[v][e] = (double)(proj[((b * NV + v) * 3 + r) * 4 + (e & 3)] * s);
    }
    __syncthreads();

    const int k = n & 63, j = (n >> 6) & 63, i = n >> 12;
    const double wx = (double)i * 0.04 - 1.28;
    const double wy = (double)j * 0.04 - 1.28;
    const double wz = (double)k * 0.04 - 1.28;

    float acc[COUT];
#pragma unroll
    for (int o = 0; o < COUT; ++o) acc[o] = 0.0f;
    int cnt = 0;

    const float* fb = feats + (size_t)b * NV * HW * COUT;

    for (int v = 0; v < NV; ++v) {
        const double* p = P[v];
        const double cz = p[8] * wx + p[9] * wy + p[10] * wz + p[11];
        if (!(cz > 0.0)) continue;
        const double cx = p[0] * wx + p[1] * wy + p[2] * wz + p[3];
        const double cy = p[4] * wx + p[5] * wy + p[6] * wz + p[7];
        const double u = rint(cx / cz);   // round-half-even == jnp.round
        const double t = rint(cy / cz);
        if (u < 0.0 || u > 63.0 || t < 0.0 || t > 63.0) continue;
        const int px = (int)u, py = (int)t;

        const float4* s4 = reinterpret_cast<const float4*>(
            fb + ((size_t)(v * HW + py * 64 + px)) * COUT);
        ++cnt;
#pragma unroll
        for (int q = 0; q < 8; ++q) {
            const float4 f = s4[q];
            acc[q * 4 + 0] += f.x;
            acc[q * 4 + 1] += f.y;
            acc[q * 4 + 2] += f.z;
            acc[q * 4 + 3] += f.w;
        }
    }

    const float sc = (cnt > 0) ? (1.0f / (float)cnt) : 0.0f;
    float* ob = out + (size_t)b * COUT * NVOX + n;
#pragma unroll
    for (int o = 0; o < COUT; ++o)
        ob[(size_t)o * NVOX] = acc[o] * sc;
}

extern "C" void kernel_launch(void* const* d_in, const int* in_sizes, int n_in,
                              void* d_out, int out_size, void* d_ws, size_t ws_size,
                              hipStream_t stream) {
    const float* vit  = (const float*)d_in[0];  // (4,12,384,64,64)
    const float* w    = (const float*)d_in[1];  // (32,384)
    const float* bias = (const float*)d_in[2];  // (32,)
    const float* proj = (const float*)d_in[3];  // (4,12,3,4)
    float* out = (float*)d_out;                 // (4,32,64,64,64)

    short* wfrag = (short*)d_ws;                           // 12288 bf16 = 24 KB
    float* feats = (float*)((char*)d_ws + 48 * 32 * 8 * 2); // 25.2 MB

    w_prep_kernel<<<6, 256, 0, stream>>>(w, wfrag);

    mv_reduce_mfma_kernel<<<3072, 256, 0, stream>>>(vit, wfrag, bias, feats);

    mv_fuse_kernel<<<4096, 256, 0, stream>>>(feats, proj, out);
}

// Round 5
// 130.856 us; speedup vs baseline: 3.3930x; 1.4071x over previous
//
#include <hip/hip_runtime.h>

#define NV 12
#define CIN 384
#define COUT 32
#define HW 4096        // 64*64 feature pixels
#define NVOX 262144    // 64^3 voxels
#define KSTEPS 12      // 384 / 32
#define KSTEP 32
#define KPAD 33        // +1 pad: ds bank rotation
#define PIXB 64        // pixels per block (4 waves x 16)

typedef __attribute__((ext_vector_type(8))) short short8v;   // 8 bf16 (4 VGPR)
typedef __attribute__((ext_vector_type(4))) short short4v;   // 4 bf16 (2 VGPR)
typedef __attribute__((ext_vector_type(4))) float f32x4;     // MFMA accum

// fp32 -> bf16 bits, round-to-nearest-even (finite data; NaN not handled).
__device__ __forceinline__ short bf16b(float x) {
    union { float f; unsigned u; } c; c.f = x;
    unsigned r = (c.u + 0x7fffu + ((c.u >> 16) & 1u)) >> 16;
    return (short)r;
}

// Prep: repack W (32x384 fp32) into MFMA A-fragment order, bf16:
// wfrag[((s*4+g)*32 + o)*8 + i] = bf16(w[o*384 + s*32 + g*8 + i])
__global__ __launch_bounds__(256) void w_prep_kernel(
    const float* __restrict__ w, short* __restrict__ wfrag)
{
    const int t = blockIdx.x * 256 + threadIdx.x;   // 0..1535
    if (t >= 48 * 32) return;
    const int sg = t >> 5, o = t & 31;
    const int s = sg >> 2, g = sg & 3;
    short8v v;
#pragma unroll
    for (int i = 0; i < 8; ++i)
        v[i] = bf16b(w[o * CIN + s * 32 + g * 8 + i]);
    *reinterpret_cast<short8v*>(wfrag + t * 8) = v;
}

// Kernel 1: channel reduce 384->32 on matrix cores, LDS-staged.
// Block = 4 waves, 64-pixel tile. Staging: thread t loads vit rows kk=t>>4 and
// kk+16 as float4 (4 contiguous pixels) -> 4x256B segments per wave-inst (1KB,
// fully coalesced). LDS transposed [pix][k] (+1 pad -> 2-way banks = free) so
// each lane's B-frag (8 k-contiguous f32) is 2 ds_read_b128.
// D layout: col(pix) = l&15, row(o) = 4*(l>>4)+reg. Output feats in bf16.
__global__ __launch_bounds__(256) void mv_reduce_mfma_kernel(
    const float* __restrict__ vit, const short* __restrict__ wfrag,
    const float* __restrict__ bias, short* __restrict__ feats)
{
    __shared__ float lds[PIXB][KPAD];        // 8448 B -> 8 blocks/CU fits

    const int bid  = blockIdx.x;             // 0..3071
    const int bv   = bid >> 6;               // 0..47
    const int pix0 = (bid & 63) * PIXB;

    const int tid  = threadIdx.x;
    const int wave = tid >> 6;
    const int l    = tid & 63;
    const int col  = l & 15;                 // pixel-in-tile / o-in-tile
    const int g    = l >> 4;                 // k-group

    const int kk  = tid >> 4;                // staging row 0..15
    const int px4 = (tid & 15) * 4;          // staging pixel quad

    const float* vbase = vit + (size_t)bv * CIN * HW + pix0;
    const short8v* wf  = reinterpret_cast<const short8v*>(wfrag);

    f32x4 acc0 = {0.f, 0.f, 0.f, 0.f};
    f32x4 acc1 = {0.f, 0.f, 0.f, 0.f};

#pragma unroll
    for (int s = 0; s < KSTEPS; ++s) {
        const float4 r0 = *reinterpret_cast<const float4*>(
            vbase + (size_t)(s * KSTEP + kk) * HW + px4);
        const float4 r1 = *reinterpret_cast<const float4*>(
            vbase + (size_t)(s * KSTEP + kk + 16) * HW + px4);

        __syncthreads();                     // prior iteration's reads done
        lds[px4 + 0][kk] = r0.x;  lds[px4 + 1][kk] = r0.y;
        lds[px4 + 2][kk] = r0.z;  lds[px4 + 3][kk] = r0.w;
        lds[px4 + 0][kk + 16] = r1.x;  lds[px4 + 1][kk + 16] = r1.y;
        lds[px4 + 2][kk + 16] = r1.z;  lds[px4 + 3][kk + 16] = r1.w;
        __syncthreads();                     // writes visible

        const float4 f0 = *reinterpret_cast<const float4*>(&lds[wave * 16 + col][8 * g]);
        const float4 f1 = *reinterpret_cast<const float4*>(&lds[wave * 16 + col][8 * g + 4]);

        short8v bfr;
        bfr[0] = bf16b(f0.x); bfr[1] = bf16b(f0.y);
        bfr[2] = bf16b(f0.z); bfr[3] = bf16b(f0.w);
        bfr[4] = bf16b(f1.x); bfr[5] = bf16b(f1.y);
        bfr[6] = bf16b(f1.z); bfr[7] = bf16b(f1.w);

        const short8v a0 = wf[(s * 4 + g) * 32 + col];        // o = col
        const short8v a1 = wf[(s * 4 + g) * 32 + 16 + col];   // o = 16 + col

        acc0 = __builtin_amdgcn_mfma_f32_16x16x32_bf16(a0, bfr, acc0, 0, 0, 0);
        acc1 = __builtin_amdgcn_mfma_f32_16x16x32_bf16(a1, bfr, acc1, 0, 0, 0);
    }

    // Store bf16: feats[bv][pix][o]; lane's 4 accum elems are o = 4g+r.
    short* dst = feats + ((size_t)bv * HW + pix0 + wave * 16 + col) * COUT;
    const float4 b0 = *reinterpret_cast<const float4*>(bias + 4 * g);
    const float4 b1 = *reinterpret_cast<const float4*>(bias + 16 + 4 * g);
    short4v o0, o1;
    o0[0] = bf16b(acc0[0] + b0.x); o0[1] = bf16b(acc0[1] + b0.y);
    o0[2] = bf16b(acc0[2] + b0.z); o0[3] = bf16b(acc0[3] + b0.w);
    o1[0] = bf16b(acc1[0] + b1.x); o1[1] = bf16b(acc1[1] + b1.y);
    o1[2] = bf16b(acc1[2] + b1.z); o1[3] = bf16b(acc1[3] + b1.w);
    *reinterpret_cast<short4v*>(dst + 4 * g) = o0;
    *reinterpret_cast<short4v*>(dst + 16 + 4 * g) = o1;
}

// Kernel 2: backproject + gather (bf16 rows, 64B aligned) + average.
// Projection math in fp64 (rint = round-half-even matches jnp.round); one
// reciprocal per view instead of two divides (error ~2^-52, negligible vs the
// reference's own 2^-24 window).
__global__ __launch_bounds__(256) void mv_fuse_kernel(
    const unsigned short* __restrict__ feats, const float* __restrict__ proj,
    float* __restrict__ out)
{
    __shared__ double P[NV][12];

    const int tid = threadIdx.x;
    const unsigned gid = blockIdx.x * 256u + tid;
    const int b = gid >> 18;            // 262144 voxels per batch
    const int n = gid & (NVOX - 1);

    if (tid < NV * 12) {
        const int v = tid / 12, e = tid - v * 12;
        const int r = e >> 2;                       // row 0..2
        const float s = (r < 2) ? 0.25f : 1.0f;     // projection[:, :, :2, :] / STRIDE
        P[v][e] = (double)(proj[((b * NV + v) * 3 + r) * 4 + (e & 3)] * s);
    }
    __syncthreads();

    const int k = n & 63, j = (n >> 6) & 63, i = n >> 12;
    const double wx = (double)i * 0.04 - 1.28;
    const double wy = (double)j * 0.04 - 1.28;
    const double wz = (double)k * 0.04 - 1.28;

    float acc[COUT];
#pragma unroll
    for (int o = 0; o < COUT; ++o) acc[o] = 0.0f;
    int cnt = 0;

    const unsigned short* fb = feats + (size_t)b * NV * HW * COUT;

    for (int v = 0; v < NV; ++v) {
        const double* p = P[v];
        const double cz = p[8] * wx + p[9] * wy + p[10] * wz + p[11];
        if (!(cz > 0.0)) continue;
        const double cx = p[0] * wx + p[1] * wy + p[2] * wz + p[3];
        const double cy = p[4] * wx + p[5] * wy + p[6] * wz + p[7];
        const double rcz = 1.0 / cz;
        const double u = rint(cx * rcz);   // round-half-even == jnp.round
        const double t = rint(cy * rcz);
        if (u < 0.0 || u > 63.0 || t < 0.0 || t > 63.0) continue;
        const int px = (int)u, py = (int)t;

        const uint4* s4 = reinterpret_cast<const uint4*>(
            fb + ((size_t)(v * HW + py * 64 + px)) * COUT);
        ++cnt;
#pragma unroll
        for (int q = 0; q < 4; ++q) {
            const uint4 u4 = s4[q];
            acc[q * 8 + 0] += __uint_as_float(u4.x << 16);
            acc[q * 8 + 1] += __uint_as_float(u4.x & 0xffff0000u);
            acc[q * 8 + 2] += __uint_as_float(u4.y << 16);
            acc[q * 8 + 3] += __uint_as_float(u4.y & 0xffff0000u);
            acc[q * 8 + 4] += __uint_as_float(u4.z << 16);
            acc[q * 8 + 5] += __uint_as_float(u4.z & 0xffff0000u);
            acc[q * 8 + 6] += __uint_as_float(u4.w << 16);
            acc[q * 8 + 7] += __uint_as_float(u4.w & 0xffff0000u);
        }
    }

    const float sc = (cnt > 0) ? (1.0f / (float)cnt) : 0.0f;
    float* ob = out + (size_t)b * COUT * NVOX + n;
#pragma unroll
    for (int o = 0; o < COUT; ++o)
        ob[(size_t)o * NVOX] = acc[o] * sc;
}

extern "C" void kernel_launch(void* const* d_in, const int* in_sizes, int n_in,
                              void* d_out, int out_size, void* d_ws, size_t ws_size,
                              hipStream_t stream) {
    const float* vit  = (const float*)d_in[0];  // (4,12,384,64,64)
    const float* w    = (const float*)d_in[1];  // (32,384)
    const float* bias = (const float*)d_in[2];  // (32,)
    const float* proj = (const float*)d_in[3];  // (4,12,3,4)
    float* out = (float*)d_out;                 // (4,32,64,64,64)

    short* wfrag = (short*)d_ws;                            // 24 KB
    short* feats = (short*)((char*)d_ws + 48 * 32 * 8 * 2); // bf16, 12.6 MB

    w_prep_kernel<<<6, 256, 0, stream>>>(w, wfrag);

    mv_reduce_mfma_kernel<<<3072, 256, 0, stream>>>(vit, wfrag, bias, feats);

    mv_fuse_kernel<<<4096, 256, 0, stream>>>(
        (const unsigned short*)feats, proj, out);
}